// Round 2
// baseline (567.297 us; speedup 1.0000x reference)
//
#include <hip/hip_runtime.h>

// receptive_attention: out[b,h,i,j] = (|i-j| <= 128) ? dot(q[i,:], k[j,:]) : 0
// B=2 H=16 L=2048 D=64 fp32.
//
// R5 = R4 with LDS shrunk to 48.75 KiB (R4's 80 KiB static __shared__ is over
// the per-workgroup cap and is the one plausible kernel-side cause of the
// container failure; everything else audits clean).
//  - band block (y=0): one 1024-thread block per 64-row strip. Q staged ONCE
//    (R3 restaged it 5x -> ~64 MB avoidable fetch). K tiles staged 2-at-a-time
//    (512 threads each, 4x2 micro-tile) with REGISTER prefetch of the next
//    pair issued before the current pair's compute. Accumulators for all <=5
//    tiles held in registers (static-indexed, fully unrolled: no scratch).
//    After the last compute barrier the masked result is flushed in TWO
//    32-row passes to an LDS Band[32][320] buffer that ALIASES the dead
//    Q/K staging arena (union = 3*64*65 floats = 48.75 KiB), each pass swept
//    to global as LINEAR 1.28 KB/row bursts — replacing R3's
//    256B-at-8KB-stride tile stores (pattern already measured bad).
//  - zero block (y=1): R3's measured-good row-linear path, one block per
//    strip: per row, threads 0..511 write the left run, 512.. the right run.
//    wl4/wr4 <= 464 < 512 always.
// MEASURED-BAD, do not reintroduce: __builtin_nontemporal_store (R2),
// transposed-K LDS staging (8-way write conflicts), 256B-at-8KB-stride sweeps.

constexpr int L = 2048;
constexpr int D = 64;
constexpr int R = 128;
constexpr int TILE = 64;
constexpr int NT = L / TILE;        // 32
constexpr int KS = D + 1;           // 65: conflict-free strided reads
constexpr int BAND_W = 5 * TILE;    // 320 band columns max per strip
constexpr int ARENA = 3 * TILE * KS; // 12480 floats = 48.75 KiB (>= 32*320)

__global__ __launch_bounds__(1024, 4)
void receptive_attention_kernel(const float* __restrict__ q,
                                const float* __restrict__ k,
                                float* __restrict__ out) {
    const int ti = blockIdx.x;      // 64-row strip
    const int bh = blockIdx.z;
    const int t  = threadIdx.x;

    const int jt_lo = (ti - 2 > 0) ? (ti - 2) : 0;
    const int jt_hi = (ti + 2 < NT - 1) ? (ti + 2) : (NT - 1);
    const int ntj   = jt_hi - jt_lo + 1;          // 3..5
    const int c0    = jt_lo * TILE;               // band start col (64-aligned)

    float* outStrip = out + (size_t)bh * L * L + (size_t)ti * TILE * L;

    if (blockIdx.y == 1) {
        // ---- zero block: per row, one masked float4 store per thread ----
        const int wl4 = jt_lo * 16;               // left-run float4 count
        const int wr4 = (NT - 1 - jt_hi) * 16;    // right-run float4 count
        const int rb4 = (jt_hi + 1) * 16;         // right-run start float4
        const float4 z = make_float4(0.f, 0.f, 0.f, 0.f);
        for (int r = 0; r < TILE; ++r) {
            float* orow = outStrip + (size_t)r * L;
            if (t < wl4) {
                *reinterpret_cast<float4*>(orow + t * 4) = z;
            } else if (t >= 512 && (t - 512) < wr4) {
                *reinterpret_cast<float4*>(orow + (rb4 + (t - 512)) * 4) = z;
            }
        }
        return;
    }

    // ---- band block ----
    // LDS arena, aliased:
    //   compute phase: Qs[64*65] at 0, K pair at +4160 (g=0) / +8320 (g=1)
    //   flush/sweep:   Band[32][320] = 10240 floats over the arena (dead then)
    __shared__ __align__(16) float smem[ARENA];   // 48.75 KiB

    float* Qs = smem;
    const int s = t & 511;          // lane-in-group
    const int g = t >> 9;           // tile-group 0/1
    float* Kb = smem + TILE * KS + g * TILE * KS;

    const float* qTile = q + ((size_t)bh * L + (size_t)ti * TILE) * D;
    const float* kBase = k + ((size_t)bh * L + (size_t)jt_lo * TILE) * D;

    // ---- initial stage: Q (all 1024 threads) + K pair 0 (tiles 0,1 valid: ntj>=3)
    {
        const int row = t >> 4;
        const int col = (t & 15) * 4;
        float4 qv = *reinterpret_cast<const float4*>(qTile + row * D + col);

        const int kr = s >> 4;                 // 0..31; second half = kr+32
        const int kc = (s & 15) * 4;
        const float* kt = kBase + (size_t)g * TILE * D;
        float4 ka = *reinterpret_cast<const float4*>(kt + kr * D + kc);
        float4 kb = *reinterpret_cast<const float4*>(kt + (kr + 32) * D + kc);

        float* qd = &Qs[row * KS + col];
        qd[0] = qv.x; qd[1] = qv.y; qd[2] = qv.z; qd[3] = qv.w;
        float* kd0 = &Kb[kr * KS + kc];
        kd0[0] = ka.x; kd0[1] = ka.y; kd0[2] = ka.z; kd0[3] = ka.w;
        float* kd1 = &Kb[(kr + 32) * KS + kc];
        kd1[0] = kb.x; kd1[1] = kb.y; kd1[2] = kb.z; kd1[3] = kb.w;
    }
    __syncthreads();

    const int tr  = (s >> 5) * 4;          // micro-tile rows (4): 0..60
    const int tc2 = (s & 31) * 2;          // micro-tile cols (2): 0..62

    float acc[3][4][2] = {};               // all indices static after unroll

    #pragma unroll
    for (int p = 0; p < 3; ++p) {
        // prefetch next K pair into registers (issued before compute)
        float4 na, nb;
        const int ntt = 2 * (p + 1) + g;
        const bool npv = (p < 2) && (ntt < ntj);
        if (npv) {
            const float* kt = kBase + (size_t)ntt * TILE * D;
            const int kr = s >> 4;
            const int kc = (s & 15) * 4;
            na = *reinterpret_cast<const float4*>(kt + kr * D + kc);
            nb = *reinterpret_cast<const float4*>(kt + (kr + 32) * D + kc);
        }

        const int tt = 2 * p + g;
        if (tt < ntj) {
            #pragma unroll 8
            for (int d = 0; d < D; ++d) {
                float q0 = Qs[(tr + 0) * KS + d];
                float q1 = Qs[(tr + 1) * KS + d];
                float q2 = Qs[(tr + 2) * KS + d];
                float q3 = Qs[(tr + 3) * KS + d];
                float k0 = Kb[(tc2 + 0) * KS + d];
                float k1 = Kb[(tc2 + 1) * KS + d];
                acc[p][0][0] += q0 * k0; acc[p][0][1] += q0 * k1;
                acc[p][1][0] += q1 * k0; acc[p][1][1] += q1 * k1;
                acc[p][2][0] += q2 * k0; acc[p][2][1] += q2 * k1;
                acc[p][3][0] += q3 * k0; acc[p][3][1] += q3 * k1;
            }
        }
        __syncthreads();                   // everyone done reading Kb
        if (npv) {
            const int kr = s >> 4;
            const int kc = (s & 15) * 4;
            float* kd0 = &Kb[kr * KS + kc];
            kd0[0] = na.x; kd0[1] = na.y; kd0[2] = na.z; kd0[3] = na.w;
            float* kd1 = &Kb[(kr + 32) * KS + kc];
            kd1[0] = nb.x; kd1[1] = nb.y; kd1[2] = nb.z; kd1[3] = nb.w;
        }
        __syncthreads();                   // staged before next round
    }

    // ---- flush+sweep in two 32-row passes (Band aliases the dead arena;
    //      all staging reads completed at the compute loop's last barrier) ----
    float* Band = smem;
    const int gi0 = ti * TILE + tr;
    const int bw4 = ntj * 16;              // float4s per band row (48/64/80)

    #pragma unroll
    for (int half = 0; half < 2; ++half) {
        const int rlo = half * 32;
        if (tr >= rlo && tr < rlo + 32) {
            #pragma unroll
            for (int p = 0; p < 3; ++p) {
                const int tt = 2 * p + g;
                if (tt < ntj) {
                    const int gj0 = (jt_lo + tt) * TILE + tc2;
                    #pragma unroll
                    for (int i = 0; i < 4; ++i) {
                        int d0 = gi0 + i - gj0;       if (d0 < 0) d0 = -d0;
                        int d1 = gi0 + i - (gj0 + 1); if (d1 < 0) d1 = -d1;
                        float2 v;
                        v.x = (d0 <= R) ? acc[p][i][0] : 0.f;
                        v.y = (d1 <= R) ? acc[p][i][1] : 0.f;
                        *reinterpret_cast<float2*>(
                            &Band[(tr - rlo + i) * BAND_W + tt * TILE + tc2]) = v;
                    }
                }
            }
        }
        __syncthreads();

        // sweep: 32 rows x bw4 float4, linear 1.28 KB bursts per row
        #pragma unroll
        for (int it = 0; it < 3; ++it) {
            const int f = t + it * 1024;   // < 3072; valid domain 32*80=2560
            if (f < 2560) {
                const int row = f / 80;    // const divisor -> magic mul
                const int c4  = f - row * 80;
                if (c4 < bw4) {
                    float4 v = *reinterpret_cast<float4*>(&Band[row * BAND_W + c4 * 4]);
                    *reinterpret_cast<float4*>(
                        outStrip + (size_t)(rlo + row) * L + c0 + c4 * 4) = v;
                }
            }
        }
        __syncthreads();                   // sweep reads done before next flush
    }
}

extern "C" void kernel_launch(void* const* d_in, const int* in_sizes, int n_in,
                              void* d_out, int out_size, void* d_ws, size_t ws_size,
                              hipStream_t stream) {
    const float* q = (const float*)d_in[0];
    const float* k = (const float*)d_in[1];
    float* out = (float*)d_out;

    dim3 grid(NT, 2, 32);   // x=strip, y=0 band / 1 zeros, z=bh
    receptive_attention_kernel<<<grid, 1024, 0, stream>>>(q, k, out);
}

// Round 3
// 552.467 us; speedup vs baseline: 1.0268x; 1.0268x over previous
//
#include <hip/hip_runtime.h>

// receptive_attention: out[b,h,i,j] = (|i-j| <= 128) ? dot(q[i,:], k[j,:]) : 0
// B=2 H=16 L=2048 D=64 fp32.
//
// R6 = R3 structure (proven 215us kernel: per-tile 256-thr band blocks +
// row-linear zero blocks, single dispatch) with two targeted changes:
//  1) Band inner loop reads LDS via ds_read_b128 with a T2-style 16B-block
//     XOR swizzle (blk = (d>>2) ^ (row>>2), stride 64, no pad):
//     8 b128 per 64 FMA vs R3's 32 b32 -> ~2x less LDS-pipe time, 4x fewer
//     read instructions. Banking hand-verified: stage writes 2-way (free),
//     K reads 2-way+broadcast (free), Q reads 4-quad broadcast (free).
//     FMA order over d unchanged (4 separate += per acc) -> bit-exact.
//  2) grid.y remapped so dispatch order alternates band/zero kinds:
//     LDS-bound and HBM-bound blocks co-resident instead of phase-separated,
//     letting zero-store HBM drain overlap band LDS compute.
// MEASURED-BAD, do not reintroduce: __builtin_nontemporal_store (R2),
// scalar-write transposed-K staging (8-way write conflicts), R5's 1024-thr
// strip-monolithic blocks (6-read/8-FMA ratio raised LDS time; 567us),
// >64KB static __shared__ (R4: container-killing launch failure).

constexpr int L = 2048;
constexpr int D = 64;
constexpr int R = 128;
constexpr int TILE = 64;
constexpr int NT = L / TILE;        // 32

__global__ __launch_bounds__(256, 4)
void receptive_attention_kernel(const float* __restrict__ q,
                                const float* __restrict__ k,
                                float* __restrict__ out) {
    const int ti = blockIdx.x;      // 64-row strip
    const int y  = blockIdx.y;      // interleaved kind
    const int bh = blockIdx.z;
    const int t  = threadIdx.x;

    // y: 0,2,4,6,8 -> band tiles 0..4 ; 1,3,5,7 -> zero segments 0..3
    const int kind = (y & 1) ? (5 + (y >> 1)) : (y >> 1);

    const int jt_lo = (ti - 2 > 0) ? (ti - 2) : 0;
    const int jt_hi = (ti + 2 < NT - 1) ? (ti + 2) : (NT - 1);

    float* outStrip = out + (size_t)bh * L * L + (size_t)ti * TILE * L;

    if (kind >= 5) {
        // ---- zero block (R3 verbatim): rows [16*(kind-5), +16) ----
        const int r0  = (kind - 5) * 16;
        const int wl4 = (jt_lo * TILE) / 4;                  // left-run float4s
        const int rb  = (jt_hi + 1) * TILE;                  // right-run start col
        const int nz4 = (L - (jt_hi - jt_lo + 1) * TILE) / 4;
        const float4 z = make_float4(0.f, 0.f, 0.f, 0.f);
        for (int r = 0; r < 16; ++r) {
            float* orow = outStrip + (size_t)(r0 + r) * L;
            for (int f = t; f < nz4; f += 256) {
                int col = (f < wl4) ? (f * 4) : (rb + (f - wl4) * 4);
                *reinterpret_cast<float4*>(orow + col) = z;
            }
        }
        return;
    }

    // ---- band tile block: tj = ti + kind - 2 ----
    const int tj = ti + kind - 2;
    if (tj < 0 || tj >= NT) return;

    // Swizzled tiles, stride 64 (32 KB total). Element (row, d) lives at
    // word row*64 + 4*(((d>>2) ^ (row>>2)) & 15) + (d&3).
    __shared__ __align__(16) float Qs[TILE * 64];
    __shared__ __align__(16) float Ks[TILE * 64];

    const float* qTile = q + ((size_t)bh * L + (size_t)ti * TILE) * D;
    const float* kTile = k + ((size_t)bh * L + (size_t)tj * TILE) * D;

    #pragma unroll
    for (int it = 0; it < 4; ++it) {
        int idx  = t + it * 256;
        int row  = idx >> 4;          // 0..63
        int col4 = idx & 15;          // 16B-block index within row
        float4 qv = *reinterpret_cast<const float4*>(qTile + row * D + col4 * 4);
        float4 kv = *reinterpret_cast<const float4*>(kTile + row * D + col4 * 4);
        int wblk = (col4 ^ (row >> 2)) & 15;
        *reinterpret_cast<float4*>(&Qs[row * 64 + wblk * 4]) = qv;
        *reinterpret_cast<float4*>(&Ks[row * 64 + wblk * 4]) = kv;
    }
    __syncthreads();

    const int tr = (t >> 4) * 4;   // micro-tile base row
    const int tc = (t & 15) * 4;   // micro-tile base col
    const int xq = (t >> 4) & 15;  // (row>>2) for all 4 q rows (tr%4==0)
    const int xk = t & 15;         // (col>>2) for all 4 k cols (tc%4==0)

    float acc[4][4] = {};
    #pragma unroll 4
    for (int b = 0; b < 16; ++b) {  // d0 = 4*b
        float4 qv[4], kv[4];
        const int qb = ((b ^ xq) & 15) * 4;
        const int kb = ((b ^ xk) & 15) * 4;
        #pragma unroll
        for (int r = 0; r < 4; ++r)
            qv[r] = *reinterpret_cast<const float4*>(&Qs[(tr + r) * 64 + qb]);
        #pragma unroll
        for (int c = 0; c < 4; ++c)
            kv[c] = *reinterpret_cast<const float4*>(&Ks[(tc + c) * 64 + kb]);
        #pragma unroll
        for (int rr = 0; rr < 4; ++rr) {
            #pragma unroll
            for (int cc = 0; cc < 4; ++cc) {
                // d-order preserved: four separate += (bit-exact vs scalar loop)
                acc[rr][cc] += qv[rr].x * kv[cc].x;
                acc[rr][cc] += qv[rr].y * kv[cc].y;
                acc[rr][cc] += qv[rr].z * kv[cc].z;
                acc[rr][cc] += qv[rr].w * kv[cc].w;
            }
        }
    }

    float* outTile = outStrip + tj * TILE;
    const int gi0 = ti * TILE + tr;
    const int gj0 = tj * TILE + tc;
    #pragma unroll
    for (int rr = 0; rr < 4; ++rr) {
        int gi = gi0 + rr;
        float4 v;
        float* vp = &v.x;
        #pragma unroll
        for (int cc = 0; cc < 4; ++cc) {
            int gj = gj0 + cc;
            int diff = gi - gj;
            if (diff < 0) diff = -diff;
            vp[cc] = (diff <= R) ? acc[rr][cc] : 0.f;
        }
        *reinterpret_cast<float4*>(outTile + (size_t)(tr + rr) * L + tc) = v;
    }
}

extern "C" void kernel_launch(void* const* d_in, const int* in_sizes, int n_in,
                              void* d_out, int out_size, void* d_ws, size_t ws_size,
                              hipStream_t stream) {
    const float* q = (const float*)d_in[0];
    const float* k = (const float*)d_in[1];
    float* out = (float*)d_out;

    dim3 grid(NT, 9, 32);   // x=strip, y=interleaved band/zero kinds, z=bh
    receptive_attention_kernel<<<grid, 256, 0, stream>>>(q, k, out);
}